// Round 4
// baseline (531.954 us; speedup 1.0000x reference)
//
#include <hip/hip_runtime.h>
#include <hip/hip_bf16.h>

#define EPS 1e-5f

constexpr int B    = 32;
constexpr int C    = 256;
constexpr int O    = 256;
constexpr int NZ   = 49;
constexpr int NX   = 961;
constexpr int NXP  = 1024;   // padded NX
constexpr int NZP  = 128;    // padded NZ rows
constexpr int C3   = 768;

typedef short  bf16x8 __attribute__((ext_vector_type(8)));
typedef float  f32x4  __attribute__((ext_vector_type(4)));

__device__ inline ushort f2bf(float f) {
    union { float f; uint u; } v; v.f = f;
    uint r = v.u + 0x7fffu + ((v.u >> 16) & 1u);   // round-to-nearest-even
    return (ushort)(r >> 16);
}

// ---------------------------------------------------------------------------
// NT MFMA GEMM (unchanged from round 2 — known-correct).
// C[b][i][j] = act( sum_k A'[b][i][k] * B'[b][j][k] ), 128x128 tile, BK=32.
// ---------------------------------------------------------------------------
template<int ACT, bool BIAS_COL, bool OUT_BF16>
__global__ __launch_bounds__(256)
void mfma_nt(const ushort* __restrict__ Abase, long sA, int lda,
             const ushort* __restrict__ Bbase, long sB, int ldb,
             void* __restrict__ Cbase, long sC, int ldc, int Nstore,
             int K,
             const float* __restrict__ bias,
             const float* __restrict__ gamma, const float* __restrict__ beta,
             const float* __restrict__ mean,  const float* __restrict__ varr)
{
    __shared__ ushort As[4096];
    __shared__ ushort Bs[4096];

    const int b   = blockIdx.z;
    const ushort* A  = Abase + (long)b * sA;
    const ushort* Bm = Bbase + (long)b * sB;
    const int i0 = blockIdx.y * 128;
    const int j0 = blockIdx.x * 128;

    const int tid  = threadIdx.x;
    const int lane = tid & 63;
    const int wid  = tid >> 6;
    const int wrow = wid >> 1, wcol = wid & 1;

    const int s0 = wid * 128 + lane;
    const int s1 = s0 + 64;
    auto soff = [](int s, int ld) {
        int row = s >> 2;
        int kq  = (s & 3) ^ ((s >> 3) & 3);
        return (long)row * ld + kq * 8;
    };
    const ushort* gA0 = A  + (long)i0 * lda + soff(s0, lda);
    const ushort* gA1 = A  + (long)i0 * lda + soff(s1, lda);
    const ushort* gB0 = Bm + (long)j0 * ldb + soff(s0, ldb);
    const ushort* gB1 = Bm + (long)j0 * ldb + soff(s1, ldb);

    ushort* lA0 = As + wid * 1024;
    ushort* lA1 = As + wid * 1024 + 512;
    ushort* lB0 = Bs + wid * 1024;
    ushort* lB1 = Bs + wid * 1024 + 512;

    const int rl = lane & 15, kq = lane >> 4;
    int aoff[4], boff[4];
    #pragma unroll
    for (int f = 0; f < 4; ++f) {
        int ra = wrow * 64 + f * 16 + rl;
        int ba = (ra * 64 + kq * 16) ^ ((ra & 6) << 3);
        aoff[f] = ba >> 1;
        int rb = wcol * 64 + f * 16 + rl;
        int bb = (rb * 64 + kq * 16) ^ ((rb & 6) << 3);
        boff[f] = bb >> 1;
    }

    f32x4 acc[4][4];
    #pragma unroll
    for (int i = 0; i < 4; ++i)
        #pragma unroll
        for (int j = 0; j < 4; ++j)
            acc[i][j] = (f32x4){0.f, 0.f, 0.f, 0.f};

    for (int k0 = 0; k0 < K; k0 += 32) {
        __builtin_amdgcn_global_load_lds((const __attribute__((address_space(1))) void*)gA0,
                                         (__attribute__((address_space(3))) void*)lA0, 16, 0, 0);
        __builtin_amdgcn_global_load_lds((const __attribute__((address_space(1))) void*)gA1,
                                         (__attribute__((address_space(3))) void*)lA1, 16, 0, 0);
        __builtin_amdgcn_global_load_lds((const __attribute__((address_space(1))) void*)gB0,
                                         (__attribute__((address_space(3))) void*)lB0, 16, 0, 0);
        __builtin_amdgcn_global_load_lds((const __attribute__((address_space(1))) void*)gB1,
                                         (__attribute__((address_space(3))) void*)lB1, 16, 0, 0);
        gA0 += 32; gA1 += 32; gB0 += 32; gB1 += 32;
        __syncthreads();

        bf16x8 av[4], bv[4];
        #pragma unroll
        for (int f = 0; f < 4; ++f) av[f] = *(const bf16x8*)(As + aoff[f]);
        #pragma unroll
        for (int f = 0; f < 4; ++f) bv[f] = *(const bf16x8*)(Bs + boff[f]);

        #pragma unroll
        for (int i = 0; i < 4; ++i)
            #pragma unroll
            for (int j = 0; j < 4; ++j)
                acc[i][j] = __builtin_amdgcn_mfma_f32_16x16x32_bf16(av[i], bv[j], acc[i][j], 0, 0, 0);
        __syncthreads();
    }

    const int jb = j0 + wcol * 64 + rl;
    const int ib = i0 + wrow * 64 + kq * 4;

    ushort* Cb16 = (ushort*)Cbase + (long)b * sC;
    float*  Cb32 = (float*)Cbase + (long)b * sC;

    #pragma unroll
    for (int fj = 0; fj < 4; ++fj) {
        int gj = jb + fj * 16;
        if (gj >= Nstore) continue;
        float sc = 1.f, sh = 0.f;
        if (ACT >= 1 && BIAS_COL) {
            float add = bias[gj];
            if (ACT == 2) {
                float inv = rsqrtf(varr[gj] + EPS);
                sc = gamma[gj] * inv;
                sh = (add - mean[gj]) * sc + beta[gj];
            } else {
                sh = add;
            }
        }
        #pragma unroll
        for (int fi = 0; fi < 4; ++fi) {
            #pragma unroll
            for (int r = 0; r < 4; ++r) {
                int gi = ib + fi * 16 + r;
                float v = acc[fi][fj][r];
                if (ACT >= 1) {
                    if (BIAS_COL) {
                        v = v * sc + sh;
                        if (ACT == 2) v = fmaxf(v, 0.f);
                    } else {
                        float add = bias[gi];
                        if (ACT == 2) {
                            float inv = rsqrtf(varr[gi] + EPS);
                            float s2 = gamma[gi] * inv;
                            v = v * s2 + (add - mean[gi]) * s2 + beta[gi];
                            v = fmaxf(v, 0.f);
                        } else {
                            v += add;
                        }
                    }
                }
                long off = (long)gi * ldc + gj;
                if (OUT_BF16) Cb16[off] = f2bf(v);
                else          Cb32[off] = v;
            }
        }
    }
}

// ---------------------------------------------------------------------------
// Flash attention (no barriers; each wave owns 16 Q rows).
//   Out[n][c] = sum_m softmax_m(Q[n]·K[m]) * V^T[c][m]
// Q: xqT-layout [b][NXP][C] (row n, k contiguous)
// K: [b][KVPAD-ish][C]     (row m, k contiguous), stride sK per batch
// V: [b][C][LDV]           (row c, m contiguous)
// Out: bf16, row stride C3 (pre-offset to the concat section by caller)
// Grid: 512 = 16 q-tiles x 32 batches, XCD-swizzled. 256 threads.
// ---------------------------------------------------------------------------
template<int KVPAD, int VALID, int LDV>
__global__ __launch_bounds__(256)
void flash_attn(const ushort* __restrict__ Qm,
                const ushort* __restrict__ Km, long sK,
                const ushort* __restrict__ Vm,
                ushort* __restrict__ Outm)
{
    __shared__ ushort plds[4][1024];   // per-wave 16x64 bf16 P tile, XOR-swizzled

    int wg = blockIdx.x;
    wg = (wg & 7) * 64 + (wg >> 3);    // XCD chunking: each XCD owns 4 batches
    const int b  = wg >> 4;
    const int qt = wg & 15;

    const int tid  = threadIdx.x;
    const int wid  = tid >> 6;
    const int lane = tid & 63;
    const int rl   = lane & 15;        // 0..15
    const int g    = lane >> 4;        // 0..3

    // Q fragments: row = lane&15 (A-frag), k = ks*32 + g*8
    const ushort* Qp = Qm + (long)b * NXP * C + (long)(qt * 64 + wid * 16 + rl) * C + g * 8;
    bf16x8 aq[8];
    #pragma unroll
    for (int ks = 0; ks < 8; ++ks) aq[ks] = *(const bf16x8*)(Qp + ks * 32);

    const ushort* Kb = Km + (long)b * sK;
    const ushort* Vb = Vm + (long)b * C * LDV;

    f32x4 o[16];
    #pragma unroll
    for (int cs = 0; cs < 16; ++cs) o[cs] = (f32x4){0.f, 0.f, 0.f, 0.f};
    f32x4 m4 = {-3.0e38f, -3.0e38f, -3.0e38f, -3.0e38f};
    f32x4 l4 = {0.f, 0.f, 0.f, 0.f};

    ushort* pw = &plds[wid][0];

    for (int kv0 = 0; kv0 < KVPAD; kv0 += 64) {
        // ---- QK^T: S tile [16 q rows][64 m cols], D-layout row=g*4+r col=rl
        f32x4 s[4];
        #pragma unroll
        for (int mt = 0; mt < 4; ++mt) s[mt] = (f32x4){0.f, 0.f, 0.f, 0.f};
        #pragma unroll
        for (int mt = 0; mt < 4; ++mt) {
            const ushort* kp = Kb + (long)(kv0 + mt * 16 + rl) * C + g * 8;
            #pragma unroll
            for (int ks = 0; ks < 8; ++ks)
                s[mt] = __builtin_amdgcn_mfma_f32_16x16x32_bf16(aq[ks], *(const bf16x8*)(kp + ks * 32), s[mt], 0, 0, 0);
        }

        // ---- mask pad columns
        if (kv0 + 64 > VALID) {
            #pragma unroll
            for (int mt = 0; mt < 4; ++mt)
                if (kv0 + mt * 16 + rl >= VALID)
                    s[mt] = (f32x4){-3.0e38f, -3.0e38f, -3.0e38f, -3.0e38f};
        }

        // ---- row max (4 subtiles in-reg, then 16-lane shfl tree)
        f32x4 pm;
        #pragma unroll
        for (int r = 0; r < 4; ++r)
            pm[r] = fmaxf(fmaxf(s[0][r], s[1][r]), fmaxf(s[2][r], s[3][r]));
        #pragma unroll
        for (int r = 0; r < 4; ++r) {
            float v = pm[r];
            v = fmaxf(v, __shfl_xor(v, 1));
            v = fmaxf(v, __shfl_xor(v, 2));
            v = fmaxf(v, __shfl_xor(v, 4));
            v = fmaxf(v, __shfl_xor(v, 8));
            pm[r] = v;
        }

        f32x4 sc;
        #pragma unroll
        for (int r = 0; r < 4; ++r) {
            float mn = fmaxf(m4[r], pm[r]);
            sc[r] = __expf(m4[r] - mn);
            m4[r] = mn;
        }

        // ---- P = exp(S - m), row sum
        #pragma unroll
        for (int mt = 0; mt < 4; ++mt)
            #pragma unroll
            for (int r = 0; r < 4; ++r)
                s[mt][r] = __expf(s[mt][r] - m4[r]);

        f32x4 rs;
        #pragma unroll
        for (int r = 0; r < 4; ++r)
            rs[r] = (s[0][r] + s[1][r]) + (s[2][r] + s[3][r]);
        #pragma unroll
        for (int r = 0; r < 4; ++r) {
            float v = rs[r];
            v += __shfl_xor(v, 1);
            v += __shfl_xor(v, 2);
            v += __shfl_xor(v, 4);
            v += __shfl_xor(v, 8);
            rs[r] = v;
        }
        #pragma unroll
        for (int r = 0; r < 4; ++r) l4[r] = l4[r] * sc[r] + rs[r];

        // ---- rescale O
        #pragma unroll
        for (int cs = 0; cs < 16; ++cs)
            #pragma unroll
            for (int r = 0; r < 4; ++r)
                o[cs][r] *= sc[r];

        // ---- P (D-layout) -> LDS bf16 (swizzled) -> A-frags
        #pragma unroll
        for (int mt = 0; mt < 4; ++mt)
            #pragma unroll
            for (int r = 0; r < 4; ++r) {
                int row = g * 4 + r;
                int idx = (row * 64 + mt * 16 + rl) ^ ((row & 7) << 3);
                pw[idx] = f2bf(s[mt][r]);
            }

        bf16x8 pa[2];
        #pragma unroll
        for (int ks2 = 0; ks2 < 2; ++ks2) {
            int idx = (rl * 64 + ks2 * 32 + g * 8) ^ ((rl & 7) << 3);
            pa[ks2] = *(const bf16x8*)(pw + idx);
        }

        // ---- PV: O[n][c] += P[n][m] * V^T[c][m]
        #pragma unroll
        for (int cs = 0; cs < 16; ++cs) {
            const ushort* vp = Vb + (long)(cs * 16 + rl) * LDV + kv0 + g * 8;
            o[cs] = __builtin_amdgcn_mfma_f32_16x16x32_bf16(pa[0], *(const bf16x8*)(vp), o[cs], 0, 0, 0);
            o[cs] = __builtin_amdgcn_mfma_f32_16x16x32_bf16(pa[1], *(const bf16x8*)(vp + 32), o[cs], 0, 0, 0);
        }
    }

    // ---- finalize: O / l, store bf16
    f32x4 inv;
    #pragma unroll
    for (int r = 0; r < 4; ++r) inv[r] = 1.0f / l4[r];

    ushort* ob = Outm + (long)b * NXP * C3 + (long)(qt * 64 + wid * 16) * C3;
    #pragma unroll
    for (int cs = 0; cs < 16; ++cs)
        #pragma unroll
        for (int r = 0; r < 4; ++r)
            ob[(long)(g * 4 + r) * C3 + cs * 16 + rl] = f2bf(o[cs][r] * inv[r]);
}

// ---------------------------------------------------------------------------
// fp32 [Cc][Nsrc] -> bf16 [Npad][Cc] transpose+convert (pad rows zeroed)
// ---------------------------------------------------------------------------
__global__ __launch_bounds__(256)
void transpose_cvt(const float* __restrict__ src, ushort* __restrict__ dst,
                   int Cc, int Nsrc, int Npad)
{
    const int bz = blockIdx.z;
    src += (long)bz * Cc * Nsrc;
    dst += (long)bz * Npad * Cc;
    const int c0 = blockIdx.x * 32, n0 = blockIdx.y * 32;
    __shared__ float t[32][33];
    const int lx = threadIdx.x & 31, ly = threadIdx.x >> 5;
    #pragma unroll
    for (int r = 0; r < 32; r += 8) {
        int n = n0 + lx;
        t[ly + r][lx] = (n < Nsrc) ? src[(long)(c0 + ly + r) * Nsrc + n] : 0.f;
    }
    __syncthreads();
    #pragma unroll
    for (int r = 0; r < 32; r += 8) {
        int n = n0 + ly + r;
        if (n < Npad) dst[(long)n * Cc + c0 + lx] = f2bf(t[lx][ly + r]);
    }
}

__global__ void cvt_bf(const float* __restrict__ src, ushort* __restrict__ dst, int n)
{
    int i = blockIdx.x * 256 + threadIdx.x;
    if (i < n) dst[i] = f2bf(src[i]);
}

// ---------------------------------------------------------------------------
extern "C" void kernel_launch(void* const* d_in, const int* in_sizes, int n_in,
                              void* d_out, int out_size, void* d_ws, size_t ws_size,
                              hipStream_t stream)
{
    const float* zf       = (const float*)d_in[0];
    const float* xf       = (const float*)d_in[1];
    const float* Wq       = (const float*)d_in[2];
    const float* bq       = (const float*)d_in[3];
    const float* Ws       = (const float*)d_in[4];
    const float* bs       = (const float*)d_in[5];
    const float* Wg       = (const float*)d_in[6];
    const float* bg       = (const float*)d_in[7];
    const float* g_gamma  = (const float*)d_in[8];
    const float* g_beta   = (const float*)d_in[9];
    const float* g_mean   = (const float*)d_in[10];
    const float* g_var    = (const float*)d_in[11];
    const float* Wfi      = (const float*)d_in[12];
    const float* bfi      = (const float*)d_in[13];
    const float* fi_gamma = (const float*)d_in[14];
    const float* fi_beta  = (const float*)d_in[15];
    const float* fi_mean  = (const float*)d_in[16];
    const float* fi_var   = (const float*)d_in[17];
    float* out = (float*)d_out;

    // ---- workspace layout ----
    char* w = (char*)d_ws;
    auto alloc = [&](long bytes) { char* p = w; w += (bytes + 255) & ~255L; return p; };
    ushort* xfT     = (ushort*)alloc(2L * B * NXP * C);        // [B][1024][256]
    ushort* xqT     = (ushort*)alloc(2L * B * NXP * C);        // [B][1024][256]  (Q and K)
    ushort* concatT = (ushort*)alloc(2L * B * NXP * C3);       // [B][1024][768]
    ushort* gate_cn = (ushort*)alloc(2L * B * C * NXP);        // [B][256][1024]  (self V^T)
    ushort* zfT     = (ushort*)alloc(2L * B * NZP * C);        // [B][128][256]
    ushort* zsT     = (ushort*)alloc(2L * B * NZP * C);        // [B][128][256]   (sim K)
    ushort* zg_cn   = (ushort*)alloc(2L * B * C * NZP);        // [B][256][128]   (sim V^T)
    ushort* Wq_bf   = (ushort*)alloc(2L * C * C);
    ushort* Ws_bf   = (ushort*)alloc(2L * C * C);
    ushort* Wg_bf   = (ushort*)alloc(2L * C * C);
    ushort* Wfi_bf  = (ushort*)alloc(2L * O * C3);

    // ---- 0) convert weights, transpose+convert activations ----
    cvt_bf<<<dim3((C * C + 255) / 256), 256, 0, stream>>>(Wq, Wq_bf, C * C);
    cvt_bf<<<dim3((C * C + 255) / 256), 256, 0, stream>>>(Ws, Ws_bf, C * C);
    cvt_bf<<<dim3((C * C + 255) / 256), 256, 0, stream>>>(Wg, Wg_bf, C * C);
    cvt_bf<<<dim3((O * C3 + 255) / 256), 256, 0, stream>>>(Wfi, Wfi_bf, O * C3);
    transpose_cvt<<<dim3(C / 32, NXP / 32, B), 256, 0, stream>>>(xf, xfT, C, NX, NXP);
    transpose_cvt<<<dim3(C / 32, NZP / 32, B), 256, 0, stream>>>(zf, zfT, C, NZ, NZP);

    // ---- 1) conv q: xqT[n][c] (Q and K for both attentions) ----
    mfma_nt<1, true, true><<<dim3(2, 8, B), 256, 0, stream>>>(
        xfT, (long)NXP * C, C, Wq_bf, 0, C,
        xqT, (long)NXP * C, C, C, C, bq, nullptr, nullptr, nullptr, nullptr);

    // ---- 2) gate -> concatT section 2 (gateT[n][c]) ----
    mfma_nt<2, true, true><<<dim3(2, 8, B), 256, 0, stream>>>(
        xfT, (long)NXP * C, C, Wg_bf, 0, C,
        concatT + 2 * C, (long)NXP * C3, C3, C, C, bg, g_gamma, g_beta, g_mean, g_var);

    // ---- 3) gate other orientation: gate_cn[c][n] (self V^T) ----
    mfma_nt<2, false, true><<<dim3(8, 2, B), 256, 0, stream>>>(
        Wg_bf, 0, C, xfT, (long)NXP * C, C,
        gate_cn, (long)C * NXP, NXP, NXP, C, bg, g_gamma, g_beta, g_mean, g_var);

    // ---- 4) conv zs: zsT[m][c] (sim K) ----
    mfma_nt<1, true, true><<<dim3(2, 1, B), 256, 0, stream>>>(
        zfT, (long)NZP * C, C, Ws_bf, 0, C,
        zsT, (long)NZP * C, C, C, C, bs, nullptr, nullptr, nullptr, nullptr);

    // ---- 5) zg_cn[c][m] (sim V^T) ----
    mfma_nt<2, false, true><<<dim3(1, 2, B), 256, 0, stream>>>(
        Wg_bf, 0, C, zfT, (long)NZP * C, C,
        zg_cn, (long)C * NZP, NZP, NZP, C, bg, g_gamma, g_beta, g_mean, g_var);

    // ---- 6) sim attention -> concatT section 0 ----
    flash_attn<64, NZ, NZP><<<dim3(512), 256, 0, stream>>>(
        xqT, zsT, (long)NZP * C, zg_cn, concatT);

    // ---- 7) self attention -> concatT section 1 ----
    flash_attn<NXP, NX, NXP><<<dim3(512), 256, 0, stream>>>(
        xqT, xqT, (long)NXP * C, gate_cn, concatT + C);

    // ---- 8) final conv: out = relu(bn(Wfi · concatT)) ----
    mfma_nt<2, false, false><<<dim3(8, 2, B), 256, 0, stream>>>(
        Wfi_bf, 0, C3, concatT, (long)NXP * C3, C3,
        out, (long)O * NX, NX, NX, C3, bfi, fi_gamma, fi_beta, fi_mean, fi_var);
}

// Round 6
// 341.058 us; speedup vs baseline: 1.5597x; 1.5597x over previous
//
#include <hip/hip_runtime.h>
#include <hip/hip_bf16.h>

#define EPS 1e-5f

constexpr int B    = 32;
constexpr int C    = 256;
constexpr int O    = 256;
constexpr int NZ   = 49;
constexpr int NX   = 961;
constexpr int NXP  = 1024;   // padded NX
constexpr int NZP  = 128;    // padded NZ rows
constexpr int C3   = 768;

typedef short  bf16x8 __attribute__((ext_vector_type(8)));
typedef float  f32x4  __attribute__((ext_vector_type(4)));

#define AS1 __attribute__((address_space(1)))
#define AS3 __attribute__((address_space(3)))

__device__ inline ushort f2bf(float f) {
    union { float f; uint u; } v; v.f = f;
    uint r = v.u + 0x7fffu + ((v.u >> 16) & 1u);   // round-to-nearest-even
    return (ushort)(r >> 16);
}

// ---------------------------------------------------------------------------
// NT MFMA GEMM (unchanged — known-correct).
// C[b][i][j] = act( sum_k A'[b][i][k] * B'[b][j][k] ), 128x128 tile, BK=32.
// ---------------------------------------------------------------------------
template<int ACT, bool BIAS_COL, bool OUT_BF16>
__global__ __launch_bounds__(256)
void mfma_nt(const ushort* __restrict__ Abase, long sA, int lda,
             const ushort* __restrict__ Bbase, long sB, int ldb,
             void* __restrict__ Cbase, long sC, int ldc, int Nstore,
             int K,
             const float* __restrict__ bias,
             const float* __restrict__ gamma, const float* __restrict__ beta,
             const float* __restrict__ mean,  const float* __restrict__ varr)
{
    __shared__ ushort As[4096];
    __shared__ ushort Bs[4096];

    const int b   = blockIdx.z;
    const ushort* A  = Abase + (long)b * sA;
    const ushort* Bm = Bbase + (long)b * sB;
    const int i0 = blockIdx.y * 128;
    const int j0 = blockIdx.x * 128;

    const int tid  = threadIdx.x;
    const int lane = tid & 63;
    const int wid  = tid >> 6;
    const int wrow = wid >> 1, wcol = wid & 1;

    const int s0 = wid * 128 + lane;
    const int s1 = s0 + 64;
    auto soff = [](int s, int ld) {
        int row = s >> 2;
        int kq  = (s & 3) ^ ((s >> 3) & 3);
        return (long)row * ld + kq * 8;
    };
    const ushort* gA0 = A  + (long)i0 * lda + soff(s0, lda);
    const ushort* gA1 = A  + (long)i0 * lda + soff(s1, lda);
    const ushort* gB0 = Bm + (long)j0 * ldb + soff(s0, ldb);
    const ushort* gB1 = Bm + (long)j0 * ldb + soff(s1, ldb);

    ushort* lA0 = As + wid * 1024;
    ushort* lA1 = As + wid * 1024 + 512;
    ushort* lB0 = Bs + wid * 1024;
    ushort* lB1 = Bs + wid * 1024 + 512;

    const int rl = lane & 15, kq = lane >> 4;
    int aoff[4], boff[4];
    #pragma unroll
    for (int f = 0; f < 4; ++f) {
        int ra = wrow * 64 + f * 16 + rl;
        int ba = (ra * 64 + kq * 16) ^ ((ra & 6) << 3);
        aoff[f] = ba >> 1;
        int rb = wcol * 64 + f * 16 + rl;
        int bb = (rb * 64 + kq * 16) ^ ((rb & 6) << 3);
        boff[f] = bb >> 1;
    }

    f32x4 acc[4][4];
    #pragma unroll
    for (int i = 0; i < 4; ++i)
        #pragma unroll
        for (int j = 0; j < 4; ++j)
            acc[i][j] = (f32x4){0.f, 0.f, 0.f, 0.f};

    for (int k0 = 0; k0 < K; k0 += 32) {
        __builtin_amdgcn_global_load_lds((const AS1 void*)gA0, (AS3 void*)lA0, 16, 0, 0);
        __builtin_amdgcn_global_load_lds((const AS1 void*)gA1, (AS3 void*)lA1, 16, 0, 0);
        __builtin_amdgcn_global_load_lds((const AS1 void*)gB0, (AS3 void*)lB0, 16, 0, 0);
        __builtin_amdgcn_global_load_lds((const AS1 void*)gB1, (AS3 void*)lB1, 16, 0, 0);
        gA0 += 32; gA1 += 32; gB0 += 32; gB1 += 32;
        __syncthreads();

        bf16x8 av[4], bv[4];
        #pragma unroll
        for (int f = 0; f < 4; ++f) av[f] = *(const bf16x8*)(As + aoff[f]);
        #pragma unroll
        for (int f = 0; f < 4; ++f) bv[f] = *(const bf16x8*)(Bs + boff[f]);

        #pragma unroll
        for (int i = 0; i < 4; ++i)
            #pragma unroll
            for (int j = 0; j < 4; ++j)
                acc[i][j] = __builtin_amdgcn_mfma_f32_16x16x32_bf16(av[i], bv[j], acc[i][j], 0, 0, 0);
        __syncthreads();
    }

    const int jb = j0 + wcol * 64 + rl;
    const int ib = i0 + wrow * 64 + kq * 4;

    ushort* Cb16 = (ushort*)Cbase + (long)b * sC;
    float*  Cb32 = (float*)Cbase + (long)b * sC;

    #pragma unroll
    for (int fj = 0; fj < 4; ++fj) {
        int gj = jb + fj * 16;
        if (gj >= Nstore) continue;
        float sc = 1.f, sh = 0.f;
        if (ACT >= 1 && BIAS_COL) {
            float add = bias[gj];
            if (ACT == 2) {
                float inv = rsqrtf(varr[gj] + EPS);
                sc = gamma[gj] * inv;
                sh = (add - mean[gj]) * sc + beta[gj];
            } else {
                sh = add;
            }
        }
        #pragma unroll
        for (int fi = 0; fi < 4; ++fi) {
            #pragma unroll
            for (int r = 0; r < 4; ++r) {
                int gi = ib + fi * 16 + r;
                float v = acc[fi][fj][r];
                if (ACT >= 1) {
                    if (BIAS_COL) {
                        v = v * sc + sh;
                        if (ACT == 2) v = fmaxf(v, 0.f);
                    } else {
                        float add = bias[gi];
                        if (ACT == 2) {
                            float inv = rsqrtf(varr[gi] + EPS);
                            float s2 = gamma[gi] * inv;
                            v = v * s2 + (add - mean[gi]) * s2 + beta[gi];
                            v = fmaxf(v, 0.f);
                        } else {
                            v += add;
                        }
                    }
                }
                long off = (long)gi * ldc + gj;
                if (OUT_BF16) Cb16[off] = f2bf(v);
                else          Cb32[off] = v;
            }
        }
    }
}

// ---------------------------------------------------------------------------
// Flash attention, LDS-staged K/V (fix for the latency-bound r4 version).
//   Out[n][c] = sum_m softmax_m(Q[n]·K[m]) * V^T[c][m]
// Q: [b][NXP][C] bf16 (row n, k contiguous)
// K: [b][*][C], stride sK per batch.  V: [b][C][LDV] (row c, m contiguous)
// Block: 4 waves, 64 q rows (16/wave). KV tile = 64 rows.
// K/V tiles staged in LDS via global_load_lds (linear dest) with involutive
// chunk-swizzle (chunk ^= row&7) applied to global source AND LDS reads.
// LDS = 32K(K) + 32K(V) + 8K(P) = 72KB -> 2 blocks/CU.
// Grid: 512 = 16 q-tiles x 32 batches, XCD-swizzled. 256 threads.
// ---------------------------------------------------------------------------
template<int KVPAD, int VALID, int LDV>
__global__ __launch_bounds__(256)
void flash_attn(const ushort* __restrict__ Qm,
                const ushort* __restrict__ Km, long sK,
                const ushort* __restrict__ Vm,
                ushort* __restrict__ Outm)
{
    __shared__ ushort Ks[64 * 256];    // 32KB: (row, kq) at row*256 + kq*8, holds global chunk kq^(row&7)
    __shared__ ushort Vs[256 * 64];    // 32KB: (c, mk)  at c*64  + mk*8, holds global m-chunk mk^(c&7)
    __shared__ ushort plds[4][1024];   // per-wave 16x64 bf16 P tile, XOR-swizzled

    int wg = blockIdx.x;
    wg = (wg & 7) * 64 + (wg >> 3);    // XCD chunking: each XCD owns 4 batches
    const int b  = wg >> 4;
    const int qt = wg & 15;

    const int tid  = threadIdx.x;
    const int wid  = tid >> 6;
    const int lane = tid & 63;
    const int rl   = lane & 15;        // 0..15
    const int g    = lane >> 4;        // 0..3

    // Q fragments: row = lane&15 (A-frag), k = ks*32 + g*8
    const ushort* Qp = Qm + (long)b * NXP * C + (long)(qt * 64 + wid * 16 + rl) * C + g * 8;
    bf16x8 aq[8];
    #pragma unroll
    for (int ks = 0; ks < 8; ++ks) aq[ks] = *(const bf16x8*)(Qp + ks * 32);

    const ushort* Kb = Km + (long)b * sK;
    const ushort* Vb = Vm + (long)b * C * LDV;

    // ---- per-thread staging source offsets (loop-invariant) ----
    // K: slot s = i*256+tid -> row s>>5, kq s&31; source chunk = kq^(row&7)
    // V: slot s = i*256+tid -> c  s>>3, mk s&7 ; source chunk = mk^(c&7)
    int offK[8], offV[8];
    #pragma unroll
    for (int i = 0; i < 8; ++i) {
        int s = i * 256 + tid;
        int row = s >> 5, kq = s & 31;
        offK[i] = row * C + ((kq ^ (row & 7)) * 8);
        int c = s >> 3, mk = s & 7;
        offV[i] = c * LDV + ((mk ^ (c & 7)) * 8);
    }

    f32x4 o[16];
    #pragma unroll
    for (int cs = 0; cs < 16; ++cs) o[cs] = (f32x4){0.f, 0.f, 0.f, 0.f};
    f32x4 m4 = {-3.0e38f, -3.0e38f, -3.0e38f, -3.0e38f};
    f32x4 l4 = {0.f, 0.f, 0.f, 0.f};

    ushort* pw = &plds[wid][0];
    const int swz = (rl & 7);          // read-side row-XOR (row low bits = rl low bits)

    for (int kv0 = 0; kv0 < KVPAD; kv0 += 64) {
        // ---- stage K tile (64 rows x 256) and V tile (256 rows x 64) ----
        const ushort* Kt = Kb + (long)kv0 * C;
        const ushort* Vt = Vb + kv0;
        #pragma unroll
        for (int i = 0; i < 8; ++i)
            __builtin_amdgcn_global_load_lds((const AS1 void*)(Kt + offK[i]),
                                             (AS3 void*)(Ks + (i * 256 + wid * 64) * 8), 16, 0, 0);
        #pragma unroll
        for (int i = 0; i < 8; ++i)
            __builtin_amdgcn_global_load_lds((const AS1 void*)(Vt + offV[i]),
                                             (AS3 void*)(Vs + (i * 256 + wid * 64) * 8), 16, 0, 0);
        __syncthreads();   // compiler emits vmcnt(0) drain before barrier

        // ---- QK^T from LDS: S tile [16 q rows][64 m], D-layout row=g*4+r col=rl
        f32x4 s[4];
        #pragma unroll
        for (int mt = 0; mt < 4; ++mt) s[mt] = (f32x4){0.f, 0.f, 0.f, 0.f};
        #pragma unroll
        for (int mt = 0; mt < 4; ++mt) {
            const ushort* krow = Ks + (mt * 16 + rl) * 256;
            #pragma unroll
            for (int ks = 0; ks < 8; ++ks) {
                const ushort* kp = krow + (((g + ks * 4) ^ swz) * 8);
                s[mt] = __builtin_amdgcn_mfma_f32_16x16x32_bf16(aq[ks], *(const bf16x8*)kp, s[mt], 0, 0, 0);
            }
        }

        // ---- mask pad columns
        if (kv0 + 64 > VALID) {
            #pragma unroll
            for (int mt = 0; mt < 4; ++mt)
                if (kv0 + mt * 16 + rl >= VALID)
                    s[mt] = (f32x4){-3.0e38f, -3.0e38f, -3.0e38f, -3.0e38f};
        }

        // ---- row max (in-reg then 16-lane shfl tree)
        f32x4 pm;
        #pragma unroll
        for (int r = 0; r < 4; ++r)
            pm[r] = fmaxf(fmaxf(s[0][r], s[1][r]), fmaxf(s[2][r], s[3][r]));
        #pragma unroll
        for (int r = 0; r < 4; ++r) {
            float v = pm[r];
            v = fmaxf(v, __shfl_xor(v, 1));
            v = fmaxf(v, __shfl_xor(v, 2));
            v = fmaxf(v, __shfl_xor(v, 4));
            v = fmaxf(v, __shfl_xor(v, 8));
            pm[r] = v;
        }

        f32x4 sc;
        #pragma unroll
        for (int r = 0; r < 4; ++r) {
            float mn = fmaxf(m4[r], pm[r]);
            sc[r] = __expf(m4[r] - mn);
            m4[r] = mn;
        }

        // ---- P = exp(S - m), row sum
        #pragma unroll
        for (int mt = 0; mt < 4; ++mt)
            #pragma unroll
            for (int r = 0; r < 4; ++r)
                s[mt][r] = __expf(s[mt][r] - m4[r]);

        f32x4 rs;
        #pragma unroll
        for (int r = 0; r < 4; ++r)
            rs[r] = (s[0][r] + s[1][r]) + (s[2][r] + s[3][r]);
        #pragma unroll
        for (int r = 0; r < 4; ++r) {
            float v = rs[r];
            v += __shfl_xor(v, 1);
            v += __shfl_xor(v, 2);
            v += __shfl_xor(v, 4);
            v += __shfl_xor(v, 8);
            rs[r] = v;
        }
        #pragma unroll
        for (int r = 0; r < 4; ++r) l4[r] = l4[r] * sc[r] + rs[r];

        // ---- rescale O
        #pragma unroll
        for (int cs = 0; cs < 16; ++cs)
            #pragma unroll
            for (int r = 0; r < 4; ++r)
                o[cs][r] *= sc[r];

        // ---- P (D-layout) -> per-wave LDS bf16 (swizzled) -> A-frags
        #pragma unroll
        for (int mt = 0; mt < 4; ++mt)
            #pragma unroll
            for (int r = 0; r < 4; ++r) {
                int row = g * 4 + r;
                int idx = (row * 64 + mt * 16 + rl) ^ ((row & 7) << 3);
                pw[idx] = f2bf(s[mt][r]);
            }

        bf16x8 pa[2];
        #pragma unroll
        for (int ks2 = 0; ks2 < 2; ++ks2) {
            int idx = (rl * 64 + ks2 * 32 + g * 8) ^ ((rl & 7) << 3);
            pa[ks2] = *(const bf16x8*)(pw + idx);
        }

        // ---- PV from LDS: O[n][c] += P[n][m] * V^T[c][m]
        #pragma unroll
        for (int cs = 0; cs < 16; ++cs) {
            const ushort* vrow = Vs + (cs * 16 + rl) * 64;
            const ushort* vp0 = vrow + ((g ^ swz) * 8);
            const ushort* vp1 = vrow + (((g + 4) ^ swz) * 8);
            o[cs] = __builtin_amdgcn_mfma_f32_16x16x32_bf16(pa[0], *(const bf16x8*)vp0, o[cs], 0, 0, 0);
            o[cs] = __builtin_amdgcn_mfma_f32_16x16x32_bf16(pa[1], *(const bf16x8*)vp1, o[cs], 0, 0, 0);
        }
        __syncthreads();   // protect Ks/Vs for next tile's staging
    }

    // ---- finalize: O / l, store bf16
    f32x4 inv;
    #pragma unroll
    for (int r = 0; r < 4; ++r) inv[r] = 1.0f / l4[r];

    ushort* ob = Outm + (long)b * NXP * C3 + (long)(qt * 64 + wid * 16) * C3;
    #pragma unroll
    for (int cs = 0; cs < 16; ++cs)
        #pragma unroll
        for (int r = 0; r < 4; ++r)
            ob[(long)(g * 4 + r) * C3 + cs * 16 + rl] = f2bf(o[cs][r] * inv[r]);
}

// ---------------------------------------------------------------------------
// fp32 [Cc][Nsrc] -> bf16 [Npad][Cc] transpose+convert (pad rows zeroed)
// ---------------------------------------------------------------------------
__global__ __launch_bounds__(256)
void transpose_cvt(const float* __restrict__ src, ushort* __restrict__ dst,
                   int Cc, int Nsrc, int Npad)
{
    const int bz = blockIdx.z;
    src += (long)bz * Cc * Nsrc;
    dst += (long)bz * Npad * Cc;
    const int c0 = blockIdx.x * 32, n0 = blockIdx.y * 32;
    __shared__ float t[32][33];
    const int lx = threadIdx.x & 31, ly = threadIdx.x >> 5;
    #pragma unroll
    for (int r = 0; r < 32; r += 8) {
        int n = n0 + lx;
        t[ly + r][lx] = (n < Nsrc) ? src[(long)(c0 + ly + r) * Nsrc + n] : 0.f;
    }
    __syncthreads();
    #pragma unroll
    for (int r = 0; r < 32; r += 8) {
        int n = n0 + ly + r;
        if (n < Npad) dst[(long)n * Cc + c0 + lx] = f2bf(t[lx][ly + r]);
    }
}

__global__ void cvt_bf(const float* __restrict__ src, ushort* __restrict__ dst, int n)
{
    int i = blockIdx.x * 256 + threadIdx.x;
    if (i < n) dst[i] = f2bf(src[i]);
}

// ---------------------------------------------------------------------------
extern "C" void kernel_launch(void* const* d_in, const int* in_sizes, int n_in,
                              void* d_out, int out_size, void* d_ws, size_t ws_size,
                              hipStream_t stream)
{
    const float* zf       = (const float*)d_in[0];
    const float* xf       = (const float*)d_in[1];
    const float* Wq       = (const float*)d_in[2];
    const float* bq       = (const float*)d_in[3];
    const float* Ws       = (const float*)d_in[4];
    const float* bs       = (const float*)d_in[5];
    const float* Wg       = (const float*)d_in[6];
    const float* bg       = (const float*)d_in[7];
    const float* g_gamma  = (const float*)d_in[8];
    const float* g_beta   = (const float*)d_in[9];
    const float* g_mean   = (const float*)d_in[10];
    const float* g_var    = (const float*)d_in[11];
    const float* Wfi      = (const float*)d_in[12];
    const float* bfi      = (const float*)d_in[13];
    const float* fi_gamma = (const float*)d_in[14];
    const float* fi_beta  = (const float*)d_in[15];
    const float* fi_mean  = (const float*)d_in[16];
    const float* fi_var   = (const float*)d_in[17];
    float* out = (float*)d_out;

    // ---- workspace layout ----
    char* w = (char*)d_ws;
    auto alloc = [&](long bytes) { char* p = w; w += (bytes + 255) & ~255L; return p; };
    ushort* xfT     = (ushort*)alloc(2L * B * NXP * C);        // [B][1024][256]
    ushort* xqT     = (ushort*)alloc(2L * B * NXP * C);        // [B][1024][256]  (Q and K)
    ushort* concatT = (ushort*)alloc(2L * B * NXP * C3);       // [B][1024][768]
    ushort* gate_cn = (ushort*)alloc(2L * B * C * NXP);        // [B][256][1024]  (self V^T)
    ushort* zfT     = (ushort*)alloc(2L * B * NZP * C);        // [B][128][256]
    ushort* zsT     = (ushort*)alloc(2L * B * NZP * C);        // [B][128][256]   (sim K)
    ushort* zg_cn   = (ushort*)alloc(2L * B * C * NZP);        // [B][256][128]   (sim V^T)
    ushort* Wq_bf   = (ushort*)alloc(2L * C * C);
    ushort* Ws_bf   = (ushort*)alloc(2L * C * C);
    ushort* Wg_bf   = (ushort*)alloc(2L * C * C);
    ushort* Wfi_bf  = (ushort*)alloc(2L * O * C3);

    // ---- 0) convert weights, transpose+convert activations ----
    cvt_bf<<<dim3((C * C + 255) / 256), 256, 0, stream>>>(Wq, Wq_bf, C * C);
    cvt_bf<<<dim3((C * C + 255) / 256), 256, 0, stream>>>(Ws, Ws_bf, C * C);
    cvt_bf<<<dim3((C * C + 255) / 256), 256, 0, stream>>>(Wg, Wg_bf, C * C);
    cvt_bf<<<dim3((O * C3 + 255) / 256), 256, 0, stream>>>(Wfi, Wfi_bf, O * C3);
    transpose_cvt<<<dim3(C / 32, NXP / 32, B), 256, 0, stream>>>(xf, xfT, C, NX, NXP);
    transpose_cvt<<<dim3(C / 32, NZP / 32, B), 256, 0, stream>>>(zf, zfT, C, NZ, NZP);

    // ---- 1) conv q: xqT[n][c] (Q and K for both attentions) ----
    mfma_nt<1, true, true><<<dim3(2, 8, B), 256, 0, stream>>>(
        xfT, (long)NXP * C, C, Wq_bf, 0, C,
        xqT, (long)NXP * C, C, C, C, bq, nullptr, nullptr, nullptr, nullptr);

    // ---- 2) gate -> concatT section 2 (gateT[n][c]) ----
    mfma_nt<2, true, true><<<dim3(2, 8, B), 256, 0, stream>>>(
        xfT, (long)NXP * C, C, Wg_bf, 0, C,
        concatT + 2 * C, (long)NXP * C3, C3, C, C, bg, g_gamma, g_beta, g_mean, g_var);

    // ---- 3) gate other orientation: gate_cn[c][n] (self V^T) ----
    mfma_nt<2, false, true><<<dim3(8, 2, B), 256, 0, stream>>>(
        Wg_bf, 0, C, xfT, (long)NXP * C, C,
        gate_cn, (long)C * NXP, NXP, NXP, C, bg, g_gamma, g_beta, g_mean, g_var);

    // ---- 4) conv zs: zsT[m][c] (sim K) ----
    mfma_nt<1, true, true><<<dim3(2, 1, B), 256, 0, stream>>>(
        zfT, (long)NZP * C, C, Ws_bf, 0, C,
        zsT, (long)NZP * C, C, C, C, bs, nullptr, nullptr, nullptr, nullptr);

    // ---- 5) zg_cn[c][m] (sim V^T) ----
    mfma_nt<2, false, true><<<dim3(1, 2, B), 256, 0, stream>>>(
        Wg_bf, 0, C, zfT, (long)NZP * C, C,
        zg_cn, (long)C * NZP, NZP, NZP, C, bg, g_gamma, g_beta, g_mean, g_var);

    // ---- 6) sim attention -> concatT section 0 ----
    flash_attn<64, NZ, NZP><<<dim3(512), 256, 0, stream>>>(
        xqT, zsT, (long)NZP * C, zg_cn, concatT);

    // ---- 7) self attention -> concatT section 1 ----
    flash_attn<NXP, NX, NXP><<<dim3(512), 256, 0, stream>>>(
        xqT, xqT, (long)NXP * C, gate_cn, concatT + C);

    // ---- 8) final conv: out = relu(bn(Wfi · concatT)) ----
    mfma_nt<2, false, false><<<dim3(8, 2, B), 256, 0, stream>>>(
        Wfi_bf, 0, C3, concatT, (long)NXP * C3, C3,
        out, (long)O * NX, NX, NX, C3, bfi, fi_gamma, fi_beta, fi_mean, fi_var);
}

// Round 7
// 331.999 us; speedup vs baseline: 1.6023x; 1.0273x over previous
//
#include <hip/hip_runtime.h>
#include <hip/hip_bf16.h>

#define EPS 1e-5f

constexpr int B    = 32;
constexpr int C    = 256;
constexpr int O    = 256;
constexpr int NZ   = 49;
constexpr int NX   = 961;
constexpr int NXP  = 1024;   // padded NX
constexpr int NZP  = 128;    // padded NZ rows
constexpr int C3   = 768;

typedef short  bf16x8 __attribute__((ext_vector_type(8)));
typedef float  f32x4  __attribute__((ext_vector_type(4)));

#define AS1 __attribute__((address_space(1)))
#define AS3 __attribute__((address_space(3)))

__device__ inline ushort f2bf(float f) {
    union { float f; uint u; } v; v.f = f;
    uint r = v.u + 0x7fffu + ((v.u >> 16) & 1u);   // round-to-nearest-even
    return (ushort)(r >> 16);
}

// ---------------------------------------------------------------------------
// NT MFMA GEMM (unchanged — known-correct).
// C[b][i][j] = act( sum_k A'[b][i][k] * B'[b][j][k] ), 128x128 tile, BK=32.
// ---------------------------------------------------------------------------
template<int ACT, bool BIAS_COL, bool OUT_BF16>
__global__ __launch_bounds__(256)
void mfma_nt(const ushort* __restrict__ Abase, long sA, int lda,
             const ushort* __restrict__ Bbase, long sB, int ldb,
             void* __restrict__ Cbase, long sC, int ldc, int Nstore,
             int K,
             const float* __restrict__ bias,
             const float* __restrict__ gamma, const float* __restrict__ beta,
             const float* __restrict__ mean,  const float* __restrict__ varr)
{
    __shared__ ushort As[4096];
    __shared__ ushort Bs[4096];

    const int b   = blockIdx.z;
    const ushort* A  = Abase + (long)b * sA;
    const ushort* Bm = Bbase + (long)b * sB;
    const int i0 = blockIdx.y * 128;
    const int j0 = blockIdx.x * 128;

    const int tid  = threadIdx.x;
    const int lane = tid & 63;
    const int wid  = tid >> 6;
    const int wrow = wid >> 1, wcol = wid & 1;

    const int s0 = wid * 128 + lane;
    const int s1 = s0 + 64;
    auto soff = [](int s, int ld) {
        int row = s >> 2;
        int kq  = (s & 3) ^ ((s >> 3) & 3);
        return (long)row * ld + kq * 8;
    };
    const ushort* gA0 = A  + (long)i0 * lda + soff(s0, lda);
    const ushort* gA1 = A  + (long)i0 * lda + soff(s1, lda);
    const ushort* gB0 = Bm + (long)j0 * ldb + soff(s0, ldb);
    const ushort* gB1 = Bm + (long)j0 * ldb + soff(s1, ldb);

    ushort* lA0 = As + wid * 1024;
    ushort* lA1 = As + wid * 1024 + 512;
    ushort* lB0 = Bs + wid * 1024;
    ushort* lB1 = Bs + wid * 1024 + 512;

    const int rl = lane & 15, kq = lane >> 4;
    int aoff[4], boff[4];
    #pragma unroll
    for (int f = 0; f < 4; ++f) {
        int ra = wrow * 64 + f * 16 + rl;
        int ba = (ra * 64 + kq * 16) ^ ((ra & 6) << 3);
        aoff[f] = ba >> 1;
        int rb = wcol * 64 + f * 16 + rl;
        int bb = (rb * 64 + kq * 16) ^ ((rb & 6) << 3);
        boff[f] = bb >> 1;
    }

    f32x4 acc[4][4];
    #pragma unroll
    for (int i = 0; i < 4; ++i)
        #pragma unroll
        for (int j = 0; j < 4; ++j)
            acc[i][j] = (f32x4){0.f, 0.f, 0.f, 0.f};

    for (int k0 = 0; k0 < K; k0 += 32) {
        __builtin_amdgcn_global_load_lds((const AS1 void*)gA0, (AS3 void*)lA0, 16, 0, 0);
        __builtin_amdgcn_global_load_lds((const AS1 void*)gA1, (AS3 void*)lA1, 16, 0, 0);
        __builtin_amdgcn_global_load_lds((const AS1 void*)gB0, (AS3 void*)lB0, 16, 0, 0);
        __builtin_amdgcn_global_load_lds((const AS1 void*)gB1, (AS3 void*)lB1, 16, 0, 0);
        gA0 += 32; gA1 += 32; gB0 += 32; gB1 += 32;
        __syncthreads();

        bf16x8 av[4], bv[4];
        #pragma unroll
        for (int f = 0; f < 4; ++f) av[f] = *(const bf16x8*)(As + aoff[f]);
        #pragma unroll
        for (int f = 0; f < 4; ++f) bv[f] = *(const bf16x8*)(Bs + boff[f]);

        #pragma unroll
        for (int i = 0; i < 4; ++i)
            #pragma unroll
            for (int j = 0; j < 4; ++j)
                acc[i][j] = __builtin_amdgcn_mfma_f32_16x16x32_bf16(av[i], bv[j], acc[i][j], 0, 0, 0);
        __syncthreads();
    }

    const int jb = j0 + wcol * 64 + rl;
    const int ib = i0 + wrow * 64 + kq * 4;

    ushort* Cb16 = (ushort*)Cbase + (long)b * sC;
    float*  Cb32 = (float*)Cbase + (long)b * sC;

    #pragma unroll
    for (int fj = 0; fj < 4; ++fj) {
        int gj = jb + fj * 16;
        if (gj >= Nstore) continue;
        float sc = 1.f, sh = 0.f;
        if (ACT >= 1 && BIAS_COL) {
            float add = bias[gj];
            if (ACT == 2) {
                float inv = rsqrtf(varr[gj] + EPS);
                sc = gamma[gj] * inv;
                sh = (add - mean[gj]) * sc + beta[gj];
            } else {
                sh = add;
            }
        }
        #pragma unroll
        for (int fi = 0; fi < 4; ++fi) {
            #pragma unroll
            for (int r = 0; r < 4; ++r) {
                int gi = ib + fi * 16 + r;
                float v = acc[fi][fj][r];
                if (ACT >= 1) {
                    if (BIAS_COL) {
                        v = v * sc + sh;
                        if (ACT == 2) v = fmaxf(v, 0.f);
                    } else {
                        float add = bias[gi];
                        if (ACT == 2) {
                            float inv = rsqrtf(varr[gi] + EPS);
                            float s2 = gamma[gi] * inv;
                            v = v * s2 + (add - mean[gi]) * s2 + beta[gi];
                            v = fmaxf(v, 0.f);
                        } else {
                            v += add;
                        }
                    }
                }
                long off = (long)gi * ldc + gj;
                if (OUT_BF16) Cb16[off] = f2bf(v);
                else          Cb32[off] = v;
            }
        }
    }
}

// ---------------------------------------------------------------------------
// Flash attention, KVBLK=32, reg-staged prefetch (T14 / 2-phase pipeline).
//   Out[n][c] = sum_m softmax_m(Q[n]·K[m]) * V^T[c][m]
// Q: [b][NXP][C] bf16. K: [b][*][C] stride sK. V: [b][C][LDV].
// Block: 4 waves, 64 q rows. Per tile: 32 KV rows.
// Staging: global->reg (linear, coalesced) issued one tile ahead; ds_write
// with XOR swizzle; reads use matching swizzle. LDS = 16K(K)+16K(V)+4K(P)
// = 36KB -> 4-block/CU capacity (2 resident with grid 512).
// Defer-max (THR=8): skip O-rescale when tile max hasn't grown past m+8.
// ---------------------------------------------------------------------------
template<int KVPAD, int VALID, int LDV>
__global__ __launch_bounds__(256)
void flash_attn(const ushort* __restrict__ Qm,
                const ushort* __restrict__ Km, long sK,
                const ushort* __restrict__ Vm,
                ushort* __restrict__ Outm)
{
    constexpr int NT = KVPAD / 32;
    __shared__ ushort Ks[32 * 256];    // 16KB: [row][chunk^(row&7)] (16B chunks)
    __shared__ ushort Vs[256 * 32];    // 16KB: [c][chunk^(c&3)]
    __shared__ ushort plds[4][512];    // per-wave 16x32 P, chunk^(row>>2)

    int wg = blockIdx.x;
    wg = (wg & 7) * 64 + (wg >> 3);    // XCD chunking (512 % 8 == 0, bijective)
    const int b  = wg >> 4;
    const int qt = wg & 15;

    const int tid  = threadIdx.x;
    const int wid  = tid >> 6;
    const int lane = tid & 63;
    const int rl   = lane & 15;
    const int g    = lane >> 4;

    // Q fragments: row = rl, k = ks*32 + g*8
    const ushort* Qp = Qm + (long)b * NXP * C + (long)(qt * 64 + wid * 16 + rl) * C + g * 8;
    bf16x8 aq[8];
    #pragma unroll
    for (int ks = 0; ks < 8; ++ks) aq[ks] = *(const bf16x8*)(Qp + ks * 32);

    const ushort* Kb = Km + (long)b * sK;
    const ushort* Vb = Vm + (long)b * C * LDV;

    // staging offsets: 1024 K-chunks + 1024 V-chunks, 4 each per thread.
    // global reads are LINEAR (coalesced); swizzle applied at ds_write.
    int offKg[4], offKl[4], offVg[4], offVl[4];
    #pragma unroll
    for (int i = 0; i < 4; ++i) {
        int ck = i * 256 + tid;
        int krow = ck >> 5, kq = ck & 31;
        offKg[i] = krow * C + kq * 8;
        offKl[i] = (krow * 32 + (kq ^ (krow & 7))) * 8;
        int vrow = ck >> 2, mk = ck & 3;
        offVg[i] = vrow * LDV + mk * 8;
        offVl[i] = (vrow * 4 + (mk ^ (vrow & 3))) * 8;
    }

    f32x4 o[16];
    #pragma unroll
    for (int cs = 0; cs < 16; ++cs) o[cs] = (f32x4){0.f, 0.f, 0.f, 0.f};
    f32x4 m4 = {-3.0e38f, -3.0e38f, -3.0e38f, -3.0e38f};
    f32x4 l4 = {0.f, 0.f, 0.f, 0.f};

    ushort* pw = &plds[wid][0];

    // prologue: load tile 0 into regs
    bf16x8 kreg[4], vreg[4];
    #pragma unroll
    for (int i = 0; i < 4; ++i) kreg[i] = *(const bf16x8*)(Kb + offKg[i]);
    #pragma unroll
    for (int i = 0; i < 4; ++i) vreg[i] = *(const bf16x8*)(Vb + offVg[i]);

    for (int t = 0; t < NT; ++t) {
        // ---- write staged tile t regs -> LDS
        #pragma unroll
        for (int i = 0; i < 4; ++i) *(bf16x8*)(Ks + offKl[i]) = kreg[i];
        #pragma unroll
        for (int i = 0; i < 4; ++i) *(bf16x8*)(Vs + offVl[i]) = vreg[i];
        __syncthreads();

        // ---- issue tile t+1 loads NOW (land during compute below)
        if (t + 1 < NT) {
            const ushort* Kt = Kb + (long)(t + 1) * 32 * C;
            const ushort* Vt = Vb + (t + 1) * 32;
            #pragma unroll
            for (int i = 0; i < 4; ++i) kreg[i] = *(const bf16x8*)(Kt + offKg[i]);
            #pragma unroll
            for (int i = 0; i < 4; ++i) vreg[i] = *(const bf16x8*)(Vt + offVg[i]);
        }

        const int kv0 = t * 32;

        // ---- QK^T: S tile [16 q rows][32 m], D-layout row=g*4+r col=mt*16+rl
        f32x4 s[2];
        s[0] = (f32x4){0.f, 0.f, 0.f, 0.f};
        s[1] = (f32x4){0.f, 0.f, 0.f, 0.f};
        #pragma unroll
        for (int mt = 0; mt < 2; ++mt) {
            const ushort* krow_p = Ks + (mt * 16 + rl) * 256;
            #pragma unroll
            for (int ks = 0; ks < 8; ++ks) {
                const ushort* kp = krow_p + (((ks * 4 + g) ^ (rl & 7)) * 8);
                s[mt] = __builtin_amdgcn_mfma_f32_16x16x32_bf16(aq[ks], *(const bf16x8*)kp, s[mt], 0, 0, 0);
            }
        }

        // ---- mask pad columns
        if (kv0 + 32 > VALID) {
            #pragma unroll
            for (int mt = 0; mt < 2; ++mt)
                if (kv0 + mt * 16 + rl >= VALID)
                    s[mt] = (f32x4){-3.0e38f, -3.0e38f, -3.0e38f, -3.0e38f};
        }

        // ---- row max
        f32x4 pm;
        #pragma unroll
        for (int r = 0; r < 4; ++r) pm[r] = fmaxf(s[0][r], s[1][r]);
        #pragma unroll
        for (int r = 0; r < 4; ++r) {
            float v = pm[r];
            v = fmaxf(v, __shfl_xor(v, 1));
            v = fmaxf(v, __shfl_xor(v, 2));
            v = fmaxf(v, __shfl_xor(v, 4));
            v = fmaxf(v, __shfl_xor(v, 8));
            pm[r] = v;
        }

        // ---- defer-max: rescale only if some row grew past m+8
        int ok = (pm[0] <= m4[0] + 8.f) && (pm[1] <= m4[1] + 8.f) &&
                 (pm[2] <= m4[2] + 8.f) && (pm[3] <= m4[3] + 8.f);
        if (!__all(ok)) {
            f32x4 sc;
            #pragma unroll
            for (int r = 0; r < 4; ++r) {
                float mn = fmaxf(m4[r], pm[r]);
                sc[r] = __expf(m4[r] - mn);
                m4[r] = mn;
            }
            #pragma unroll
            for (int r = 0; r < 4; ++r) l4[r] *= sc[r];
            #pragma unroll
            for (int cs = 0; cs < 16; ++cs)
                #pragma unroll
                for (int r = 0; r < 4; ++r) o[cs][r] *= sc[r];
        }

        // ---- P = exp(S - m), row sum
        #pragma unroll
        for (int mt = 0; mt < 2; ++mt)
            #pragma unroll
            for (int r = 0; r < 4; ++r)
                s[mt][r] = __expf(s[mt][r] - m4[r]);

        f32x4 rs;
        #pragma unroll
        for (int r = 0; r < 4; ++r) rs[r] = s[0][r] + s[1][r];
        #pragma unroll
        for (int r = 0; r < 4; ++r) {
            float v = rs[r];
            v += __shfl_xor(v, 1);
            v += __shfl_xor(v, 2);
            v += __shfl_xor(v, 4);
            v += __shfl_xor(v, 8);
            l4[r] += v;
        }

        // ---- P (D-layout) -> per-wave LDS bf16 (chunk^(row>>2) swizzle)
        #pragma unroll
        for (int mt = 0; mt < 2; ++mt)
            #pragma unroll
            for (int r = 0; r < 4; ++r) {
                int row = g * 4 + r;
                int chunk = mt * 2 + (rl >> 3);
                int idx = row * 32 + ((chunk ^ (row >> 2)) * 8) + (rl & 7);
                pw[idx] = f2bf(s[mt][r]);
            }

        // ---- P A-frag: row = rl, chunk g
        bf16x8 pa = *(const bf16x8*)(pw + rl * 32 + ((g ^ (rl >> 2)) * 8));

        // ---- PV: O[n][c] += P[n][m] * V^T[c][m]
        #pragma unroll
        for (int cs = 0; cs < 16; ++cs) {
            int c = cs * 16 + rl;
            const ushort* vp = Vs + c * 32 + ((g ^ (c & 3)) * 8);
            o[cs] = __builtin_amdgcn_mfma_f32_16x16x32_bf16(pa, *(const bf16x8*)vp, o[cs], 0, 0, 0);
        }
        __syncthreads();   // all reads done before next tile's ds_writes
    }

    // ---- finalize: O / l, store bf16
    f32x4 inv;
    #pragma unroll
    for (int r = 0; r < 4; ++r) inv[r] = 1.0f / l4[r];

    ushort* ob = Outm + (long)b * NXP * C3 + (long)(qt * 64 + wid * 16) * C3;
    #pragma unroll
    for (int cs = 0; cs < 16; ++cs)
        #pragma unroll
        for (int r = 0; r < 4; ++r)
            ob[(long)(g * 4 + r) * C3 + cs * 16 + rl] = f2bf(o[cs][r] * inv[r]);
}

// ---------------------------------------------------------------------------
// fp32 [Cc][Nsrc] -> bf16 [Npad][Cc] transpose+convert (pad rows zeroed)
// ---------------------------------------------------------------------------
__global__ __launch_bounds__(256)
void transpose_cvt(const float* __restrict__ src, ushort* __restrict__ dst,
                   int Cc, int Nsrc, int Npad)
{
    const int bz = blockIdx.z;
    src += (long)bz * Cc * Nsrc;
    dst += (long)bz * Npad * Cc;
    const int c0 = blockIdx.x * 32, n0 = blockIdx.y * 32;
    __shared__ float t[32][33];
    const int lx = threadIdx.x & 31, ly = threadIdx.x >> 5;
    #pragma unroll
    for (int r = 0; r < 32; r += 8) {
        int n = n0 + lx;
        t[ly + r][lx] = (n < Nsrc) ? src[(long)(c0 + ly + r) * Nsrc + n] : 0.f;
    }
    __syncthreads();
    #pragma unroll
    for (int r = 0; r < 32; r += 8) {
        int n = n0 + ly + r;
        if (n < Npad) dst[(long)n * Cc + c0 + lx] = f2bf(t[lx][ly + r]);
    }
}

__global__ void cvt_bf(const float* __restrict__ src, ushort* __restrict__ dst, int n)
{
    int i = blockIdx.x * 256 + threadIdx.x;
    if (i < n) dst[i] = f2bf(src[i]);
}

// ---------------------------------------------------------------------------
extern "C" void kernel_launch(void* const* d_in, const int* in_sizes, int n_in,
                              void* d_out, int out_size, void* d_ws, size_t ws_size,
                              hipStream_t stream)
{
    const float* zf       = (const float*)d_in[0];
    const float* xf       = (const float*)d_in[1];
    const float* Wq       = (const float*)d_in[2];
    const float* bq       = (const float*)d_in[3];
    const float* Ws       = (const float*)d_in[4];
    const float* bs       = (const float*)d_in[5];
    const float* Wg       = (const float*)d_in[6];
    const float* bg       = (const float*)d_in[7];
    const float* g_gamma  = (const float*)d_in[8];
    const float* g_beta   = (const float*)d_in[9];
    const float* g_mean   = (const float*)d_in[10];
    const float* g_var    = (const float*)d_in[11];
    const float* Wfi      = (const float*)d_in[12];
    const float* bfi      = (const float*)d_in[13];
    const float* fi_gamma = (const float*)d_in[14];
    const float* fi_beta  = (const float*)d_in[15];
    const float* fi_mean  = (const float*)d_in[16];
    const float* fi_var   = (const float*)d_in[17];
    float* out = (float*)d_out;

    // ---- workspace layout ----
    char* w = (char*)d_ws;
    auto alloc = [&](long bytes) { char* p = w; w += (bytes + 255) & ~255L; return p; };
    ushort* xfT     = (ushort*)alloc(2L * B * NXP * C);        // [B][1024][256]
    ushort* xqT     = (ushort*)alloc(2L * B * NXP * C);        // [B][1024][256]  (Q and K)
    ushort* concatT = (ushort*)alloc(2L * B * NXP * C3);       // [B][1024][768]
    ushort* gate_cn = (ushort*)alloc(2L * B * C * NXP);        // [B][256][1024]  (self V^T)
    ushort* zfT     = (ushort*)alloc(2L * B * NZP * C);        // [B][128][256]
    ushort* zsT     = (ushort*)alloc(2L * B * NZP * C);        // [B][128][256]   (sim K)
    ushort* zg_cn   = (ushort*)alloc(2L * B * C * NZP);        // [B][256][128]   (sim V^T)
    ushort* Wq_bf   = (ushort*)alloc(2L * C * C);
    ushort* Ws_bf   = (ushort*)alloc(2L * C * C);
    ushort* Wg_bf   = (ushort*)alloc(2L * C * C);
    ushort* Wfi_bf  = (ushort*)alloc(2L * O * C3);

    // ---- 0) convert weights, transpose+convert activations ----
    cvt_bf<<<dim3((C * C + 255) / 256), 256, 0, stream>>>(Wq, Wq_bf, C * C);
    cvt_bf<<<dim3((C * C + 255) / 256), 256, 0, stream>>>(Ws, Ws_bf, C * C);
    cvt_bf<<<dim3((C * C + 255) / 256), 256, 0, stream>>>(Wg, Wg_bf, C * C);
    cvt_bf<<<dim3((O * C3 + 255) / 256), 256, 0, stream>>>(Wfi, Wfi_bf, O * C3);
    transpose_cvt<<<dim3(C / 32, NXP / 32, B), 256, 0, stream>>>(xf, xfT, C, NX, NXP);
    transpose_cvt<<<dim3(C / 32, NZP / 32, B), 256, 0, stream>>>(zf, zfT, C, NZ, NZP);

    // ---- 1) conv q: xqT[n][c] (Q and K for both attentions) ----
    mfma_nt<1, true, true><<<dim3(2, 8, B), 256, 0, stream>>>(
        xfT, (long)NXP * C, C, Wq_bf, 0, C,
        xqT, (long)NXP * C, C, C, C, bq, nullptr, nullptr, nullptr, nullptr);

    // ---- 2) gate -> concatT section 2 (gateT[n][c]) ----
    mfma_nt<2, true, true><<<dim3(2, 8, B), 256, 0, stream>>>(
        xfT, (long)NXP * C, C, Wg_bf, 0, C,
        concatT + 2 * C, (long)NXP * C3, C3, C, C, bg, g_gamma, g_beta, g_mean, g_var);

    // ---- 3) gate other orientation: gate_cn[c][n] (self V^T) ----
    mfma_nt<2, false, true><<<dim3(8, 2, B), 256, 0, stream>>>(
        Wg_bf, 0, C, xfT, (long)NXP * C, C,
        gate_cn, (long)C * NXP, NXP, NXP, C, bg, g_gamma, g_beta, g_mean, g_var);

    // ---- 4) conv zs: zsT[m][c] (sim K) ----
    mfma_nt<1, true, true><<<dim3(2, 1, B), 256, 0, stream>>>(
        zfT, (long)NZP * C, C, Ws_bf, 0, C,
        zsT, (long)NZP * C, C, C, C, bs, nullptr, nullptr, nullptr, nullptr);

    // ---- 5) zg_cn[c][m] (sim V^T) ----
    mfma_nt<2, false, true><<<dim3(1, 2, B), 256, 0, stream>>>(
        Wg_bf, 0, C, zfT, (long)NZP * C, C,
        zg_cn, (long)C * NZP, NZP, NZP, C, bg, g_gamma, g_beta, g_mean, g_var);

    // ---- 6) sim attention -> concatT section 0 ----
    flash_attn<64, NZ, NZP><<<dim3(512), 256, 0, stream>>>(
        xqT, zsT, (long)NZP * C, zg_cn, concatT);

    // ---- 7) self attention -> concatT section 1 (992 = 31 tiles of 32) ----
    flash_attn<992, NX, NXP><<<dim3(512), 256, 0, stream>>>(
        xqT, xqT, (long)NXP * C, gate_cn, concatT + C);

    // ---- 8) final conv: out = relu(bn(Wfi · concatT)) ----
    mfma_nt<2, false, false><<<dim3(8, 2, B), 256, 0, stream>>>(
        Wfi_bf, 0, C3, concatT, (long)NXP * C3, C3,
        out, (long)O * NX, NX, NX, C3, bfi, fi_gamma, fi_beta, fi_mean, fi_var);
}

// Round 8
// 306.818 us; speedup vs baseline: 1.7338x; 1.0821x over previous
//
#include <hip/hip_runtime.h>
#include <hip/hip_bf16.h>

#define EPS 1e-5f

constexpr int B    = 32;
constexpr int C    = 256;
constexpr int O    = 256;
constexpr int NZ   = 49;
constexpr int NX   = 961;
constexpr int NXP  = 1024;   // padded NX
constexpr int NZP  = 128;    // padded NZ rows
constexpr int C3   = 768;

typedef short  bf16x8 __attribute__((ext_vector_type(8)));
typedef float  f32x4  __attribute__((ext_vector_type(4)));
typedef float  f32x16 __attribute__((ext_vector_type(16)));

#define AS1 __attribute__((address_space(1)))
#define AS3 __attribute__((address_space(3)))

__device__ inline ushort f2bf(float f) {
    union { float f; uint u; } v; v.f = f;
    uint r = v.u + 0x7fffu + ((v.u >> 16) & 1u);   // round-to-nearest-even
    return (ushort)(r >> 16);
}

// ---------------------------------------------------------------------------
// NT MFMA GEMM (unchanged — known-correct).
// ---------------------------------------------------------------------------
template<int ACT, bool BIAS_COL, bool OUT_BF16>
__global__ __launch_bounds__(256)
void mfma_nt(const ushort* __restrict__ Abase, long sA, int lda,
             const ushort* __restrict__ Bbase, long sB, int ldb,
             void* __restrict__ Cbase, long sC, int ldc, int Nstore,
             int K,
             const float* __restrict__ bias,
             const float* __restrict__ gamma, const float* __restrict__ beta,
             const float* __restrict__ mean,  const float* __restrict__ varr)
{
    __shared__ ushort As[4096];
    __shared__ ushort Bs[4096];

    const int b   = blockIdx.z;
    const ushort* A  = Abase + (long)b * sA;
    const ushort* Bm = Bbase + (long)b * sB;
    const int i0 = blockIdx.y * 128;
    const int j0 = blockIdx.x * 128;

    const int tid  = threadIdx.x;
    const int lane = tid & 63;
    const int wid  = tid >> 6;
    const int wrow = wid >> 1, wcol = wid & 1;

    const int s0 = wid * 128 + lane;
    const int s1 = s0 + 64;
    auto soff = [](int s, int ld) {
        int row = s >> 2;
        int kq  = (s & 3) ^ ((s >> 3) & 3);
        return (long)row * ld + kq * 8;
    };
    const ushort* gA0 = A  + (long)i0 * lda + soff(s0, lda);
    const ushort* gA1 = A  + (long)i0 * lda + soff(s1, lda);
    const ushort* gB0 = Bm + (long)j0 * ldb + soff(s0, ldb);
    const ushort* gB1 = Bm + (long)j0 * ldb + soff(s1, ldb);

    ushort* lA0 = As + wid * 1024;
    ushort* lA1 = As + wid * 1024 + 512;
    ushort* lB0 = Bs + wid * 1024;
    ushort* lB1 = Bs + wid * 1024 + 512;

    const int rl = lane & 15, kq = lane >> 4;
    int aoff[4], boff[4];
    #pragma unroll
    for (int f = 0; f < 4; ++f) {
        int ra = wrow * 64 + f * 16 + rl;
        int ba = (ra * 64 + kq * 16) ^ ((ra & 6) << 3);
        aoff[f] = ba >> 1;
        int rb = wcol * 64 + f * 16 + rl;
        int bb = (rb * 64 + kq * 16) ^ ((rb & 6) << 3);
        boff[f] = bb >> 1;
    }

    f32x4 acc[4][4];
    #pragma unroll
    for (int i = 0; i < 4; ++i)
        #pragma unroll
        for (int j = 0; j < 4; ++j)
            acc[i][j] = (f32x4){0.f, 0.f, 0.f, 0.f};

    for (int k0 = 0; k0 < K; k0 += 32) {
        __builtin_amdgcn_global_load_lds((const AS1 void*)gA0, (AS3 void*)lA0, 16, 0, 0);
        __builtin_amdgcn_global_load_lds((const AS1 void*)gA1, (AS3 void*)lA1, 16, 0, 0);
        __builtin_amdgcn_global_load_lds((const AS1 void*)gB0, (AS3 void*)lB0, 16, 0, 0);
        __builtin_amdgcn_global_load_lds((const AS1 void*)gB1, (AS3 void*)lB1, 16, 0, 0);
        gA0 += 32; gA1 += 32; gB0 += 32; gB1 += 32;
        __syncthreads();

        bf16x8 av[4], bv[4];
        #pragma unroll
        for (int f = 0; f < 4; ++f) av[f] = *(const bf16x8*)(As + aoff[f]);
        #pragma unroll
        for (int f = 0; f < 4; ++f) bv[f] = *(const bf16x8*)(Bs + boff[f]);

        #pragma unroll
        for (int i = 0; i < 4; ++i)
            #pragma unroll
            for (int j = 0; j < 4; ++j)
                acc[i][j] = __builtin_amdgcn_mfma_f32_16x16x32_bf16(av[i], bv[j], acc[i][j], 0, 0, 0);
        __syncthreads();
    }

    const int jb = j0 + wcol * 64 + rl;
    const int ib = i0 + wrow * 64 + kq * 4;

    ushort* Cb16 = (ushort*)Cbase + (long)b * sC;
    float*  Cb32 = (float*)Cbase + (long)b * sC;

    #pragma unroll
    for (int fj = 0; fj < 4; ++fj) {
        int gj = jb + fj * 16;
        if (gj >= Nstore) continue;
        float sc = 1.f, sh = 0.f;
        if (ACT >= 1 && BIAS_COL) {
            float add = bias[gj];
            if (ACT == 2) {
                float inv = rsqrtf(varr[gj] + EPS);
                sc = gamma[gj] * inv;
                sh = (add - mean[gj]) * sc + beta[gj];
            } else {
                sh = add;
            }
        }
        #pragma unroll
        for (int fi = 0; fi < 4; ++fi) {
            #pragma unroll
            for (int r = 0; r < 4; ++r) {
                int gi = ib + fi * 16 + r;
                float v = acc[fi][fj][r];
                if (ACT >= 1) {
                    if (BIAS_COL) {
                        v = v * sc + sh;
                        if (ACT == 2) v = fmaxf(v, 0.f);
                    } else {
                        float add = bias[gi];
                        if (ACT == 2) {
                            float inv = rsqrtf(varr[gi] + EPS);
                            float s2 = gamma[gi] * inv;
                            v = v * s2 + (add - mean[gi]) * s2 + beta[gi];
                            v = fmaxf(v, 0.f);
                        } else {
                            v += add;
                        }
                    }
                }
                long off = (long)gi * ldc + gj;
                if (OUT_BF16) Cb16[off] = f2bf(v);
                else          Cb32[off] = v;
            }
        }
    }
}

// ---------------------------------------------------------------------------
// Fused flash attention (sim + self), 32x32x16 MFMA, swapped operands.
// Block: 4 waves x 32 q rows = 128 q rows. Grid: 8 qtiles x 32 batches = 256.
// Per phase: loop KV tiles of 32 rows; K/V double-buffered in LDS via
// global_load_lds (linear dest, inverse-swizzled source; involutive chunk
// swizzles: K ch^=m, V ch^=(c>>1)&3). One barrier per tile.
// QK^T computed as mfma(K,Q): D col=lane&31=q -> softmax is lane-local
// (in-reg over 16 + one shfl_xor(32)). P->A-frag via 8 shfl_xor(32) on
// packed bf16 pairs. PV: mfma(P, V^T): D col=c, row=q(reg,h).
// ---------------------------------------------------------------------------
__global__ __launch_bounds__(256, 1)
void flash2(const ushort* __restrict__ xqT,
            const ushort* __restrict__ zsT,
            const ushort* __restrict__ zg_cn,
            const ushort* __restrict__ gate_cn,
            ushort* __restrict__ concatT)
{
    __shared__ ushort SK[2][32 * 256];   // [buf][m][ch'] ch'=ch^m, 16B chunks
    __shared__ ushort SV[2][256 * 32];   // [buf][c][ch'] ch'=ch^((c>>1)&3)

    int wg = blockIdx.x;
    wg = (wg & 7) * 32 + (wg >> 3);      // XCD chunking: 4 batches per XCD
    const int b  = wg >> 3;
    const int qt = wg & 7;

    const int tid = threadIdx.x;
    const int w   = tid >> 6;
    const int l   = tid & 63;
    const int l31 = l & 31;
    const int h   = l >> 5;

    // ---- Q B-frags: row q = l31 (within wave's 32), k = ks*16 + h*8 ----
    const long qrow = (long)b * NXP + qt * 128 + w * 32 + l31;
    const ushort* Qp = xqT + qrow * C + h * 8;
    bf16x8 bq[16];
    #pragma unroll
    for (int ks = 0; ks < 16; ++ks) bq[ks] = *(const bf16x8*)(Qp + ks * 16);

    // ---- staging: per thread 4 K chunks + 4 V chunks per tile ----
    int mS[4], chS[4], cS[4], ch2S[4];
    #pragma unroll
    for (int i = 0; i < 4; ++i) {
        int slot = i * 256 + tid;
        mS[i]  = slot >> 5; chS[i]  = slot & 31;
        cS[i]  = slot >> 2; ch2S[i] = slot & 3;
    }

    auto STAGE = [&](int buf, int kv0, const ushort* Kb, const ushort* Vb, int ldv) {
        #pragma unroll
        for (int i = 0; i < 4; ++i) {
            int slot = i * 256 + tid;
            const ushort* ks_src = Kb + (long)(kv0 + mS[i]) * C + ((chS[i] ^ mS[i]) << 3);
            __builtin_amdgcn_global_load_lds((const AS1 void*)ks_src,
                                             (AS3 void*)(&SK[buf][slot << 3]), 16, 0, 0);
            const ushort* vs_src = Vb + (long)cS[i] * ldv + kv0 + ((ch2S[i] ^ ((cS[i] >> 1) & 3)) << 3);
            __builtin_amdgcn_global_load_lds((const AS1 void*)vs_src,
                                             (AS3 void*)(&SV[buf][slot << 3]), 16, 0, 0);
        }
    };

    const int vsw = (l31 >> 1) & 3;      // V read swizzle term ((c>>1)&3, ct*32 even)

    // ============== phase runner ==============
    auto run_phase = [&](const ushort* Kb, const ushort* Vb, int ldv, int NT,
                         int VALID, ushort* osec) {
        f32x16 o[8];
        #pragma unroll
        for (int ct = 0; ct < 8; ++ct)
            #pragma unroll
            for (int r = 0; r < 16; ++r) o[ct][r] = 0.f;
        float mq = -3.0e38f, lq = 0.f;

        STAGE(0, 0, Kb, Vb, ldv);
        __syncthreads();                 // drain + visible

        for (int t = 0; t < NT; ++t) {
            const int buf = t & 1;
            const int kv0 = t * 32;
            if (t + 1 < NT) STAGE(buf ^ 1, kv0 + 32, Kb, Vb, ldv);

            // ---- QK^T (swapped): s = sum_ks mfma(K, Q) ----
            f32x16 s;
            #pragma unroll
            for (int r = 0; r < 16; ++r) s[r] = 0.f;
            #pragma unroll
            for (int ks = 0; ks < 16; ++ks) {
                const bf16x8 kf = *(const bf16x8*)(&SK[buf][l31 * 256 + (((ks * 2 + h) ^ l31) << 3)]);
                s = __builtin_amdgcn_mfma_f32_32x32x16_bf16(kf, bq[ks], s, 0, 0, 0);
            }

            // ---- mask pad m (per-reg; m = (r&3)+8*(r>>2)+4h) ----
            if (kv0 + 32 > VALID) {
                #pragma unroll
                for (int r = 0; r < 16; ++r) {
                    int mloc = (r & 3) + 8 * (r >> 2) + 4 * h;
                    if (kv0 + mloc >= VALID) s[r] = -3.0e38f;
                }
            }

            // ---- row max (lane-local q = l31) ----
            float pm = s[0];
            #pragma unroll
            for (int r = 1; r < 16; ++r) pm = fmaxf(pm, s[r]);
            pm = fmaxf(pm, __shfl_xor(pm, 32));

            // ---- defer-max rescale ----
            if (!__all(pm <= mq + 8.f)) {
                float mn = fmaxf(mq, pm);
                float sc = __expf(mq - mn);
                mq = mn; lq *= sc;
                #pragma unroll
                for (int r = 0; r < 16; ++r) {
                    float scr = __shfl(sc, (r & 3) + 8 * (r >> 2) + 4 * h);
                    #pragma unroll
                    for (int ct = 0; ct < 8; ++ct) o[ct][r] *= scr;
                }
            }

            // ---- P = exp(S - m), row sum ----
            float p[16]; float ps = 0.f;
            #pragma unroll
            for (int r = 0; r < 16; ++r) { p[r] = __expf(s[r] - mq); ps += p[r]; }
            ps += __shfl_xor(ps, 32);
            lq += ps;

            // ---- pack P to bf16 pairs; exchange across h via shfl_xor(32) ----
            uint P[8], X[8];
            #pragma unroll
            for (int i = 0; i < 8; ++i)
                P[i] = (uint)f2bf(p[2 * i]) | ((uint)f2bf(p[2 * i + 1]) << 16);
            #pragma unroll
            for (int i = 0; i < 8; ++i)
                X[i] = (uint)__shfl_xor((int)P[i], 32);

            union { uint u[4]; bf16x8 v; } pa0, pa1;
            pa0.u[0] = h ? X[2] : P[0];
            pa0.u[1] = h ? X[3] : P[1];
            pa0.u[2] = h ? P[2] : X[0];
            pa0.u[3] = h ? P[3] : X[1];
            pa1.u[0] = h ? X[6] : P[4];
            pa1.u[1] = h ? X[7] : P[5];
            pa1.u[2] = h ? P[6] : X[4];
            pa1.u[3] = h ? P[7] : X[5];

            // ---- PV: o[ct] += mfma(P, V^T) ----
            #pragma unroll
            for (int ct = 0; ct < 8; ++ct) {
                const int vrow = (ct * 32 + l31) * 32;
                const bf16x8 v0 = *(const bf16x8*)(&SV[buf][vrow + ((h ^ vsw) << 3)]);
                o[ct] = __builtin_amdgcn_mfma_f32_32x32x16_bf16(pa0.v, v0, o[ct], 0, 0, 0);
                const bf16x8 v1 = *(const bf16x8*)(&SV[buf][vrow + (((2 + h) ^ vsw) << 3)]);
                o[ct] = __builtin_amdgcn_mfma_f32_32x32x16_bf16(pa1.v, v1, o[ct], 0, 0, 0);
            }
            __syncthreads();             // t+1 staged & all reads of buf done
        }

        // ---- finalize: O / l, store bf16 ----
        #pragma unroll
        for (int r = 0; r < 16; ++r) {
            float lr = __shfl(lq, (r & 3) + 8 * (r >> 2) + 4 * h);
            float inv = 1.0f / lr;
            int qr = w * 32 + (r & 3) + 8 * (r >> 2) + 4 * h;
            #pragma unroll
            for (int ct = 0; ct < 8; ++ct)
                osec[(long)qr * C3 + ct * 32 + l31] = f2bf(o[ct][r] * inv);
        }
    };

    ushort* obase = concatT + ((long)b * NXP + qt * 128) * C3;

    // phase 1: sim attention (K=zsT, V^T=zg_cn) -> section 0
    run_phase(zsT + (long)b * NZP * C, zg_cn + (long)b * C * NZP, NZP,
              2, NZ, obase);
    // phase 2: self attention (K=xqT, V^T=gate_cn) -> section 1
    run_phase(xqT + (long)b * NXP * C, gate_cn + (long)b * C * NXP, NXP,
              31, NX, obase + C);
}

// ---------------------------------------------------------------------------
// fp32 [Cc][Nsrc] -> bf16 [Npad][Cc] transpose+convert (pad rows zeroed)
// ---------------------------------------------------------------------------
__global__ __launch_bounds__(256)
void transpose_cvt(const float* __restrict__ src, ushort* __restrict__ dst,
                   int Cc, int Nsrc, int Npad)
{
    const int bz = blockIdx.z;
    src += (long)bz * Cc * Nsrc;
    dst += (long)bz * Npad * Cc;
    const int c0 = blockIdx.x * 32, n0 = blockIdx.y * 32;
    __shared__ float t[32][33];
    const int lx = threadIdx.x & 31, ly = threadIdx.x >> 5;
    #pragma unroll
    for (int r = 0; r < 32; r += 8) {
        int n = n0 + lx;
        t[ly + r][lx] = (n < Nsrc) ? src[(long)(c0 + ly + r) * Nsrc + n] : 0.f;
    }
    __syncthreads();
    #pragma unroll
    for (int r = 0; r < 32; r += 8) {
        int n = n0 + ly + r;
        if (n < Npad) dst[(long)n * Cc + c0 + lx] = f2bf(t[lx][ly + r]);
    }
}

__global__ void cvt_bf(const float* __restrict__ src, ushort* __restrict__ dst, int n)
{
    int i = blockIdx.x * 256 + threadIdx.x;
    if (i < n) dst[i] = f2bf(src[i]);
}

// ---------------------------------------------------------------------------
extern "C" void kernel_launch(void* const* d_in, const int* in_sizes, int n_in,
                              void* d_out, int out_size, void* d_ws, size_t ws_size,
                              hipStream_t stream)
{
    const float* zf       = (const float*)d_in[0];
    const float* xf       = (const float*)d_in[1];
    const float* Wq       = (const float*)d_in[2];
    const float* bq       = (const float*)d_in[3];
    const float* Ws       = (const float*)d_in[4];
    const float* bs       = (const float*)d_in[5];
    const float* Wg       = (const float*)d_in[6];
    const float* bg       = (const float*)d_in[7];
    const float* g_gamma  = (const float*)d_in[8];
    const float* g_beta   = (const float*)d_in[9];
    const float* g_mean   = (const float*)d_in[10];
    const float* g_var    = (const float*)d_in[11];
    const float* Wfi      = (const float*)d_in[12];
    const float* bfi      = (const float*)d_in[13];
    const float* fi_gamma = (const float*)d_in[14];
    const float* fi_beta  = (const float*)d_in[15];
    const float* fi_mean  = (const float*)d_in[16];
    const float* fi_var   = (const float*)d_in[17];
    float* out = (float*)d_out;

    // ---- workspace layout ----
    char* w = (char*)d_ws;
    auto alloc = [&](long bytes) { char* p = w; w += (bytes + 255) & ~255L; return p; };
    ushort* xfT     = (ushort*)alloc(2L * B * NXP * C);        // [B][1024][256]
    ushort* xqT     = (ushort*)alloc(2L * B * NXP * C);        // [B][1024][256]  (Q and K)
    ushort* concatT = (ushort*)alloc(2L * B * NXP * C3);       // [B][1024][768]
    ushort* gate_cn = (ushort*)alloc(2L * B * C * NXP);        // [B][256][1024]  (self V^T)
    ushort* zfT     = (ushort*)alloc(2L * B * NZP * C);        // [B][128][256]
    ushort* zsT     = (ushort*)alloc(2L * B * NZP * C);        // [B][128][256]   (sim K)
    ushort* zg_cn   = (ushort*)alloc(2L * B * C * NZP);        // [B][256][128]   (sim V^T)
    ushort* Wq_bf   = (ushort*)alloc(2L * C * C);
    ushort* Ws_bf   = (ushort*)alloc(2L * C * C);
    ushort* Wg_bf   = (ushort*)alloc(2L * C * C);
    ushort* Wfi_bf  = (ushort*)alloc(2L * O * C3);

    // ---- 0) convert weights, transpose+convert activations ----
    cvt_bf<<<dim3((C * C + 255) / 256), 256, 0, stream>>>(Wq, Wq_bf, C * C);
    cvt_bf<<<dim3((C * C + 255) / 256), 256, 0, stream>>>(Ws, Ws_bf, C * C);
    cvt_bf<<<dim3((C * C + 255) / 256), 256, 0, stream>>>(Wg, Wg_bf, C * C);
    cvt_bf<<<dim3((O * C3 + 255) / 256), 256, 0, stream>>>(Wfi, Wfi_bf, O * C3);
    transpose_cvt<<<dim3(C / 32, NXP / 32, B), 256, 0, stream>>>(xf, xfT, C, NX, NXP);
    transpose_cvt<<<dim3(C / 32, NZP / 32, B), 256, 0, stream>>>(zf, zfT, C, NZ, NZP);

    // ---- 1) conv q: xqT[n][c] (Q and K for both attentions) ----
    mfma_nt<1, true, true><<<dim3(2, 8, B), 256, 0, stream>>>(
        xfT, (long)NXP * C, C, Wq_bf, 0, C,
        xqT, (long)NXP * C, C, C, C, bq, nullptr, nullptr, nullptr, nullptr);

    // ---- 2) gate -> concatT section 2 (gateT[n][c]) ----
    mfma_nt<2, true, true><<<dim3(2, 8, B), 256, 0, stream>>>(
        xfT, (long)NXP * C, C, Wg_bf, 0, C,
        concatT + 2 * C, (long)NXP * C3, C3, C, C, bg, g_gamma, g_beta, g_mean, g_var);

    // ---- 3) gate other orientation: gate_cn[c][n] (self V^T) ----
    mfma_nt<2, false, true><<<dim3(8, 2, B), 256, 0, stream>>>(
        Wg_bf, 0, C, xfT, (long)NXP * C, C,
        gate_cn, (long)C * NXP, NXP, NXP, C, bg, g_gamma, g_beta, g_mean, g_var);

    // ---- 4) conv zs: zsT[m][c] (sim K) ----
    mfma_nt<1, true, true><<<dim3(2, 1, B), 256, 0, stream>>>(
        zfT, (long)NZP * C, C, Ws_bf, 0, C,
        zsT, (long)NZP * C, C, C, C, bs, nullptr, nullptr, nullptr, nullptr);

    // ---- 5) zg_cn[c][m] (sim V^T) ----
    mfma_nt<2, false, true><<<dim3(1, 2, B), 256, 0, stream>>>(
        Wg_bf, 0, C, zfT, (long)NZP * C, C,
        zg_cn, (long)C * NZP, NZP, NZP, C, bg, g_gamma, g_beta, g_mean, g_var);

    // ---- 6) fused sim + self attention -> concatT sections 0,1 ----
    flash2<<<dim3(256), 256, 0, stream>>>(xqT, zsT, zg_cn, gate_cn, concatT);

    // ---- 7) final conv: out = relu(bn(Wfi · concatT)) ----
    mfma_nt<2, false, false><<<dim3(8, 2, B), 256, 0, stream>>>(
        Wfi_bf, 0, C3, concatT, (long)NXP * C3, C3,
        out, (long)O * NX, NX, NX, C3, bfi, fi_gamma, fi_beta, fi_mean, fi_var);
}